// Round 1
// baseline (8213.598 us; speedup 1.0000x reference)
//
#include <hip/hip_runtime.h>
#include <math.h>

#define BROWS  131072
#define FRAME  267
#define HDIM   512
#define LATENT 256
#define KCODES 1024

// ======================= fp32 tiled GEMM =======================
// C[M,N] = act(A_eff @ W + bias); W row-major [K,N]; C row-major ldc=N.
// BM=128, BN=128, BK=16, 256 threads, 8x8 micro-tile.
// AKIND: 0 = plain A [M,K] (requires K%16==0; used with K=512)
//        1 = concat(x[row,0:267], c[row,0:267])          K=534
//        2 = concat(embedT[ind[row],0:256], c[row,0:267]) K=523
template<int AKIND, bool RELU, bool NVEC>
__global__ __launch_bounds__(256, 2)
void gemm_k(const float* __restrict__ A,
            const float* __restrict__ xin,
            const float* __restrict__ cin,
            const int*   __restrict__ ind,
            const float* __restrict__ embedT,
            const float* __restrict__ W,
            const float* __restrict__ bias,
            float* __restrict__ C,
            int N, int K)
{
    // As padded to 136: transposed stores hit 4 distinct banks (2-way max, free);
    // 136*4=544 is 16B-multiple so As rows stay b128-readable.
    __shared__ float As[16][136];
    __shared__ float Bs[16][128];

    const int tid = threadIdx.x;
    const int tx = tid & 15, ty = tid >> 4;
    const int rowBase = blockIdx.y * 128;
    const int colBase = blockIdx.x * 128;

    const int arow = tid >> 1;          // 0..127: A row within tile
    const int aseg = (tid & 1) * 8;     // k sub-segment 0/8
    const int brow = tid >> 4;          // 0..15 : W row within k-tile
    const int bcol = (tid & 15) * 8;    // 0..120
    const int grow = rowBase + arow;

    int indr = 0;
    if constexpr (AKIND == 2) indr = ind[grow];

    float acc[8][8];
    #pragma unroll
    for (int i = 0; i < 8; ++i)
        #pragma unroll
        for (int j = 0; j < 8; ++j) acc[i][j] = 0.f;

    const int KT = (K + 15) >> 4;
    for (int kt = 0; kt < KT; ++kt) {
        const int k0 = kt << 4;

        // ---- global loads (before barrier so they overlap prior compute) ----
        float av[8];
        if constexpr (AKIND == 0) {
            const float4* ap = reinterpret_cast<const float4*>(A + (size_t)grow * K + (k0 + aseg));
            float4 a0 = ap[0], a1 = ap[1];
            av[0]=a0.x; av[1]=a0.y; av[2]=a0.z; av[3]=a0.w;
            av[4]=a1.x; av[5]=a1.y; av[6]=a1.z; av[7]=a1.w;
        } else if constexpr (AKIND == 1) {
            #pragma unroll
            for (int j = 0; j < 8; ++j) {
                int k = k0 + aseg + j;
                float v = 0.f;
                if (k < FRAME)          v = xin[(size_t)grow * FRAME + k];
                else if (k < 2 * FRAME) v = cin[(size_t)grow * FRAME + (k - FRAME)];
                av[j] = v;
            }
        } else {
            int kseg = k0 + aseg;
            if (kseg + 7 < LATENT) {   // 8-aligned segments never straddle 256
                const float4* ap = reinterpret_cast<const float4*>(embedT + (size_t)indr * LATENT + kseg);
                float4 a0 = ap[0], a1 = ap[1];
                av[0]=a0.x; av[1]=a0.y; av[2]=a0.z; av[3]=a0.w;
                av[4]=a1.x; av[5]=a1.y; av[6]=a1.z; av[7]=a1.w;
            } else {
                #pragma unroll
                for (int j = 0; j < 8; ++j) {
                    int k = kseg + j;
                    float v = 0.f;
                    if (k < LATENT)              v = embedT[(size_t)indr * LATENT + k];
                    else if (k < LATENT + FRAME) v = cin[(size_t)grow * FRAME + (k - LATENT)];
                    av[j] = v;
                }
            }
        }

        float wv[8];
        {
            const int kw = k0 + brow;
            if (kw < K) {
                if constexpr (NVEC) {
                    const float4* wp = reinterpret_cast<const float4*>(W + (size_t)kw * N + colBase + bcol);
                    float4 w0 = wp[0], w1 = wp[1];
                    wv[0]=w0.x; wv[1]=w0.y; wv[2]=w0.z; wv[3]=w0.w;
                    wv[4]=w1.x; wv[5]=w1.y; wv[6]=w1.z; wv[7]=w1.w;
                } else {
                    #pragma unroll
                    for (int j = 0; j < 8; ++j) {
                        int col = colBase + bcol + j;
                        wv[j] = (col < N) ? W[(size_t)kw * N + col] : 0.f;
                    }
                }
            } else {
                #pragma unroll
                for (int j = 0; j < 8; ++j) wv[j] = 0.f;
            }
        }

        __syncthreads();   // protect previous iteration's LDS reads
        #pragma unroll
        for (int j = 0; j < 8; ++j) As[aseg + j][arow] = av[j];
        *reinterpret_cast<float4*>(&Bs[brow][bcol])     = make_float4(wv[0],wv[1],wv[2],wv[3]);
        *reinterpret_cast<float4*>(&Bs[brow][bcol + 4]) = make_float4(wv[4],wv[5],wv[6],wv[7]);
        __syncthreads();

        #pragma unroll
        for (int k = 0; k < 16; ++k) {
            float4 a0 = *reinterpret_cast<const float4*>(&As[k][ty*8]);
            float4 a1 = *reinterpret_cast<const float4*>(&As[k][ty*8+4]);
            float4 b0 = *reinterpret_cast<const float4*>(&Bs[k][tx*8]);
            float4 b1 = *reinterpret_cast<const float4*>(&Bs[k][tx*8+4]);
            float a[8] = {a0.x,a0.y,a0.z,a0.w,a1.x,a1.y,a1.z,a1.w};
            float b[8] = {b0.x,b0.y,b0.z,b0.w,b1.x,b1.y,b1.z,b1.w};
            #pragma unroll
            for (int i = 0; i < 8; ++i)
                #pragma unroll
                for (int j = 0; j < 8; ++j)
                    acc[i][j] = fmaf(a[i], b[j], acc[i][j]);
        }
    }

    // ---- epilogue: bias + relu + store ----
    #pragma unroll
    for (int i = 0; i < 8; ++i) {
        const int row = rowBase + ty * 8 + i;
        float* crow = C + (size_t)row * N;
        if constexpr (NVEC) {
            const int col = colBase + tx * 8;
            float v[8];
            #pragma unroll
            for (int j = 0; j < 8; ++j) {
                float t = acc[i][j] + bias[col + j];
                if constexpr (RELU) t = fmaxf(t, 0.f);
                v[j] = t;
            }
            *reinterpret_cast<float4*>(crow + col)     = make_float4(v[0],v[1],v[2],v[3]);
            *reinterpret_cast<float4*>(crow + col + 4) = make_float4(v[4],v[5],v[6],v[7]);
        } else {
            #pragma unroll
            for (int j = 0; j < 8; ++j) {
                const int col = colBase + tx * 8 + j;
                if (col < N) {
                    float t = acc[i][j] + bias[col];
                    if constexpr (RELU) t = fmaxf(t, 0.f);
                    crow[col] = t;
                }
            }
        }
    }
}

// ======================= VQ argmin =======================
// Block = 64 rows. Loops 16 code-tiles (64 codes each) over full K=256.
// score_k = ||e_k||^2 - 2 mu.e_k  (||mu||^2 cancels in comparisons).
// Tie-break = lowest code index (matches argmax(-dist) first-max semantics).
__global__ __launch_bounds__(256, 2)
void vq_k(const float* __restrict__ mu,     // [B,256]
          const float* __restrict__ embed,  // [256,1024]
          const float* __restrict__ e2,     // [1024]
          int* __restrict__ ind,
          unsigned int* __restrict__ hist,
          float* __restrict__ lossAcc)
{
    __shared__ float As[16][68];     // 68 pad: transposed stores conflict-free, rows b128-aligned
    __shared__ float Es[16][64];
    __shared__ float e2s[KCODES];
    __shared__ float rbest[64][17];
    __shared__ int   ridx[64][17];
    __shared__ float mu2p[64][4];
    __shared__ float lrow[64];

    const int tid = threadIdx.x;
    const int tx = tid & 15, ty = tid >> 4;
    const int rowBase = blockIdx.x * 64;

    const int arow = tid >> 2;        // 0..63
    const int acol = (tid & 3) * 4;   // 0,4,8,12
    const int brow = tid >> 4;        // 0..15
    const int bcol = (tid & 15) * 4;  // 0..60

    #pragma unroll
    for (int i = 0; i < 4; ++i) e2s[tid + i * 256] = e2[tid + i * 256];

    float best[4]; int bidx[4];
    #pragma unroll
    for (int i = 0; i < 4; ++i) { best[i] = 3.4e38f; bidx[i] = 0; }
    float mu2 = 0.f;

    for (int ct = 0; ct < 16; ++ct) {
        float acc[4][4];
        #pragma unroll
        for (int i = 0; i < 4; ++i)
            #pragma unroll
            for (int j = 0; j < 4; ++j) acc[i][j] = 0.f;

        for (int kt = 0; kt < 16; ++kt) {
            const int k0 = kt << 4;
            float4 a4 = *reinterpret_cast<const float4*>(mu + (size_t)(rowBase + arow) * LATENT + (k0 + acol));
            float4 b4 = *reinterpret_cast<const float4*>(embed + (size_t)(k0 + brow) * KCODES + ct * 64 + bcol);
            if (ct == 0) mu2 += a4.x*a4.x + a4.y*a4.y + a4.z*a4.z + a4.w*a4.w;
            __syncthreads();
            As[acol+0][arow] = a4.x; As[acol+1][arow] = a4.y;
            As[acol+2][arow] = a4.z; As[acol+3][arow] = a4.w;
            *reinterpret_cast<float4*>(&Es[brow][bcol]) = b4;
            __syncthreads();
            #pragma unroll
            for (int k = 0; k < 16; ++k) {
                float4 af = *reinterpret_cast<const float4*>(&As[k][ty*4]);
                float4 bf = *reinterpret_cast<const float4*>(&Es[k][tx*4]);
                float a[4] = {af.x,af.y,af.z,af.w};
                float b[4] = {bf.x,bf.y,bf.z,bf.w};
                #pragma unroll
                for (int i = 0; i < 4; ++i)
                    #pragma unroll
                    for (int j = 0; j < 4; ++j)
                        acc[i][j] = fmaf(a[i], b[j], acc[i][j]);
            }
        }
        #pragma unroll
        for (int j = 0; j < 4; ++j) {
            const int code = ct * 64 + tx * 4 + j;   // ascending within thread
            const float ev = e2s[code];
            #pragma unroll
            for (int i = 0; i < 4; ++i) {
                float s = fmaf(-2.f, acc[i][j], ev);
                if (s < best[i]) { best[i] = s; bidx[i] = code; }
            }
        }
    }

    #pragma unroll
    for (int i = 0; i < 4; ++i) { rbest[ty*4+i][tx] = best[i]; ridx[ty*4+i][tx] = bidx[i]; }
    mu2p[arow][tid & 3] = mu2;
    __syncthreads();

    if (tid < 64) {
        float bb = rbest[tid][0]; int bi = ridx[tid][0];
        #pragma unroll
        for (int t = 1; t < 16; ++t) {
            float v = rbest[tid][t]; int vi = ridx[tid][t];
            if (v < bb || (v == bb && vi < bi)) { bb = v; bi = vi; }
        }
        ind[rowBase + tid] = bi;
        atomicAdd(&hist[bi], 1u);
        float m2 = mu2p[tid][0] + mu2p[tid][1] + mu2p[tid][2] + mu2p[tid][3];
        lrow[tid] = m2 + bb;              // ||mu - e_best||^2
    }
    __syncthreads();
    if (tid == 0) {
        float s = 0.f;
        #pragma unroll
        for (int r = 0; r < 64; ++r) s += lrow[r];
        atomicAdd(lossAcc, s);            // one atomic per block (2048 total)
    }
}

// ======================= small helpers =======================
__global__ void e2_k(const float* __restrict__ embed, float* __restrict__ e2)
{
    int n = blockIdx.x * 256 + threadIdx.x;   // 1024 total
    float s = 0.f;
    for (int d = 0; d < LATENT; ++d) {
        float v = embed[(size_t)d * KCODES + n];
        s = fmaf(v, v, s);
    }
    e2[n] = s;
}

__global__ void tr_k(const float* __restrict__ embed, float* __restrict__ embedT)
{
    // embedT[n][d] = embed[d][n]; 256x1024 -> 1024x256. grid (32, 8), 256 thr.
    __shared__ float t[32][33];
    const int tx = threadIdx.x & 31, ty = threadIdx.x >> 5;  // ty 0..7
    #pragma unroll
    for (int i = 0; i < 4; ++i) {
        int d = blockIdx.y * 32 + ty + i * 8;
        t[ty + i * 8][tx] = embed[(size_t)d * KCODES + blockIdx.x * 32 + tx];
    }
    __syncthreads();
    #pragma unroll
    for (int i = 0; i < 4; ++i) {
        int n = blockIdx.x * 32 + ty + i * 8;
        embedT[(size_t)n * LATENT + blockIdx.y * 32 + tx] = t[tx][ty + i * 8];
    }
}

__global__ void fin_k(const unsigned int* __restrict__ hist,
                      const float* __restrict__ lossAcc,
                      float* __restrict__ out2)
{
    __shared__ double sh[256];
    const int tid = threadIdx.x;
    double s = 0.0;
    for (int i = tid; i < KCODES; i += 256) {
        double p = (double)hist[i] / (double)BROWS;
        s += p * log(p + 1e-10);
    }
    sh[tid] = s; __syncthreads();
    for (int off = 128; off > 0; off >>= 1) {
        if (tid < off) sh[tid] += sh[tid + off];
        __syncthreads();
    }
    if (tid == 0) {
        out2[0] = lossAcc[0] / ((float)BROWS * (float)LATENT);   // loss
        out2[1] = (float)exp(-sh[0]);                            // perplexity
    }
}

// ======================= launch =======================
extern "C" void kernel_launch(void* const* d_in, const int* in_sizes, int n_in,
                              void* d_out, int out_size, void* d_ws, size_t ws_size,
                              hipStream_t stream)
{
    const float* x    = (const float*)d_in[0];
    const float* c    = (const float*)d_in[1];
    const float* W1   = (const float*)d_in[2];  const float* b1  = (const float*)d_in[3];
    const float* W2   = (const float*)d_in[4];  const float* b2  = (const float*)d_in[5];
    const float* W3   = (const float*)d_in[6];  const float* b3  = (const float*)d_in[7];
    const float* Wmu  = (const float*)d_in[8];  const float* bmu = (const float*)d_in[9];
    const float* W4   = (const float*)d_in[10]; const float* b4  = (const float*)d_in[11];
    const float* W5   = (const float*)d_in[12]; const float* b5  = (const float*)d_in[13];
    const float* W6   = (const float*)d_in[14]; const float* b6  = (const float*)d_in[15];
    const float* Wo   = (const float*)d_in[16]; const float* bo  = (const float*)d_in[17];
    const float* embed= (const float*)d_in[18];

    float* out = (float*)d_out;

    // workspace layout (~538 MB)
    char* ws = (char*)d_ws;
    float* buf0 = (float*)ws;  ws += (size_t)BROWS * HDIM * sizeof(float);
    float* buf1 = (float*)ws;  ws += (size_t)BROWS * HDIM * sizeof(float);
    int*   ind  = (int*)ws;    ws += (size_t)BROWS * sizeof(int);
    float* embedT = (float*)ws; ws += (size_t)KCODES * LATENT * sizeof(float);
    float* e2   = (float*)ws;  ws += KCODES * sizeof(float);
    unsigned int* hist = (unsigned int*)ws; ws += KCODES * sizeof(unsigned int);
    float* lossAcc = (float*)ws; ws += 16;

    // zero accumulators (hist + lossAcc are contiguous)
    hipMemsetAsync(hist, 0, KCODES * sizeof(unsigned int) + 16, stream);
    e2_k<<<dim3(4), dim3(256), 0, stream>>>(embed, e2);
    tr_k<<<dim3(32, 8), dim3(256), 0, stream>>>(embed, embedT);

    const dim3 blk(256);
    const dim3 g512(4, BROWS / 128);
    const dim3 g256(2, BROWS / 128);
    const dim3 g267(3, BROWS / 128);

    // ---- encoder (fp32 to protect argmin) ----
    gemm_k<1, true,  true ><<<g512, blk, 0, stream>>>(nullptr, x, c, nullptr, nullptr, W1,  b1,  buf0, 512, 534);
    gemm_k<0, true,  true ><<<g512, blk, 0, stream>>>(buf0, nullptr, nullptr, nullptr, nullptr, W2,  b2,  buf1, 512, 512);
    gemm_k<0, true,  true ><<<g512, blk, 0, stream>>>(buf1, nullptr, nullptr, nullptr, nullptr, W3,  b3,  buf0, 512, 512);
    gemm_k<0, false, true ><<<g256, blk, 0, stream>>>(buf0, nullptr, nullptr, nullptr, nullptr, Wmu, bmu, buf1, 256, 512);

    // ---- vector quantizer (mu = buf1) ----
    vq_k<<<dim3(BROWS / 64), blk, 0, stream>>>(buf1, embed, e2, ind, hist, lossAcc);

    // ---- decoder ----
    gemm_k<2, true,  true ><<<g512, blk, 0, stream>>>(nullptr, nullptr, c, ind, embedT, W4, b4, buf0, 512, 523);
    gemm_k<0, true,  true ><<<g512, blk, 0, stream>>>(buf0, nullptr, nullptr, nullptr, nullptr, W5, b5, buf1, 512, 512);
    gemm_k<0, true,  true ><<<g512, blk, 0, stream>>>(buf1, nullptr, nullptr, nullptr, nullptr, W6, b6, buf0, 512, 512);
    gemm_k<0, false, false><<<g267, blk, 0, stream>>>(buf0, nullptr, nullptr, nullptr, nullptr, Wo, bo, out, 267, 512);

    // ---- loss + perplexity ----
    fin_k<<<dim3(1), dim3(256), 0, stream>>>(hist, lossAcc, out + (size_t)BROWS * FRAME);
}

// Round 2
// 8144.149 us; speedup vs baseline: 1.0085x; 1.0085x over previous
//
#include <hip/hip_runtime.h>
#include <math.h>

#define BROWS  131072
#define FRAME  267
#define HDIM   512
#define LATENT 256
#define KCODES 1024

// ======================= fp32 tiled GEMM =======================
// C[M,N] = act(A_eff @ W + bias); W row-major [K,N]; C row-major ldc=N.
// BM=128, BN=128, BK=16, 256 threads, 8x8 micro-tile.
// AKIND: 0 = plain A [M,K] (requires K%16==0; used with K=512)
//        1 = concat(x[row,0:267], c[row,0:267])          K=534
//        2 = concat(embedT[ind[row],0:256], c[row,0:267]) K=523
template<int AKIND, bool RELU, bool NVEC>
__global__ __launch_bounds__(256, 2)
void gemm_k(const float* __restrict__ A,
            const float* __restrict__ xin,
            const float* __restrict__ cin,
            const int*   __restrict__ ind,
            const float* __restrict__ embedT,
            const float* __restrict__ W,
            const float* __restrict__ bias,
            float* __restrict__ C,
            int N, int K)
{
    __shared__ float As[16][136];
    __shared__ float Bs[16][128];

    const int tid = threadIdx.x;
    const int tx = tid & 15, ty = tid >> 4;
    const int rowBase = blockIdx.y * 128;
    const int colBase = blockIdx.x * 128;

    const int arow = tid >> 1;          // 0..127: A row within tile
    const int aseg = (tid & 1) * 8;     // k sub-segment 0/8
    const int brow = tid >> 4;          // 0..15 : W row within k-tile
    const int bcol = (tid & 15) * 8;    // 0..120
    const int grow = rowBase + arow;

    int indr = 0;
    if constexpr (AKIND == 2) indr = ind[grow];

    float acc[8][8];
    #pragma unroll
    for (int i = 0; i < 8; ++i)
        #pragma unroll
        for (int j = 0; j < 8; ++j) acc[i][j] = 0.f;

    const int KT = (K + 15) >> 4;
    for (int kt = 0; kt < KT; ++kt) {
        const int k0 = kt << 4;

        float av[8];
        if constexpr (AKIND == 0) {
            const float4* ap = reinterpret_cast<const float4*>(A + (size_t)grow * K + (k0 + aseg));
            float4 a0 = ap[0], a1 = ap[1];
            av[0]=a0.x; av[1]=a0.y; av[2]=a0.z; av[3]=a0.w;
            av[4]=a1.x; av[5]=a1.y; av[6]=a1.z; av[7]=a1.w;
        } else if constexpr (AKIND == 1) {
            #pragma unroll
            for (int j = 0; j < 8; ++j) {
                int k = k0 + aseg + j;
                float v = 0.f;
                if (k < FRAME)          v = xin[(size_t)grow * FRAME + k];
                else if (k < 2 * FRAME) v = cin[(size_t)grow * FRAME + (k - FRAME)];
                av[j] = v;
            }
        } else {
            int kseg = k0 + aseg;
            if (kseg + 7 < LATENT) {
                const float4* ap = reinterpret_cast<const float4*>(embedT + (size_t)indr * LATENT + kseg);
                float4 a0 = ap[0], a1 = ap[1];
                av[0]=a0.x; av[1]=a0.y; av[2]=a0.z; av[3]=a0.w;
                av[4]=a1.x; av[5]=a1.y; av[6]=a1.z; av[7]=a1.w;
            } else {
                #pragma unroll
                for (int j = 0; j < 8; ++j) {
                    int k = kseg + j;
                    float v = 0.f;
                    if (k < LATENT)              v = embedT[(size_t)indr * LATENT + k];
                    else if (k < LATENT + FRAME) v = cin[(size_t)grow * FRAME + (k - LATENT)];
                    av[j] = v;
                }
            }
        }

        float wv[8];
        {
            const int kw = k0 + brow;
            if (kw < K) {
                if constexpr (NVEC) {
                    const float4* wp = reinterpret_cast<const float4*>(W + (size_t)kw * N + colBase + bcol);
                    float4 w0 = wp[0], w1 = wp[1];
                    wv[0]=w0.x; wv[1]=w0.y; wv[2]=w0.z; wv[3]=w0.w;
                    wv[4]=w1.x; wv[5]=w1.y; wv[6]=w1.z; wv[7]=w1.w;
                } else {
                    #pragma unroll
                    for (int j = 0; j < 8; ++j) {
                        int col = colBase + bcol + j;
                        wv[j] = (col < N) ? W[(size_t)kw * N + col] : 0.f;
                    }
                }
            } else {
                #pragma unroll
                for (int j = 0; j < 8; ++j) wv[j] = 0.f;
            }
        }

        __syncthreads();
        #pragma unroll
        for (int j = 0; j < 8; ++j) As[aseg + j][arow] = av[j];
        *reinterpret_cast<float4*>(&Bs[brow][bcol])     = make_float4(wv[0],wv[1],wv[2],wv[3]);
        *reinterpret_cast<float4*>(&Bs[brow][bcol + 4]) = make_float4(wv[4],wv[5],wv[6],wv[7]);
        __syncthreads();

        #pragma unroll
        for (int k = 0; k < 16; ++k) {
            float4 a0 = *reinterpret_cast<const float4*>(&As[k][ty*8]);
            float4 a1 = *reinterpret_cast<const float4*>(&As[k][ty*8+4]);
            float4 b0 = *reinterpret_cast<const float4*>(&Bs[k][tx*8]);
            float4 b1 = *reinterpret_cast<const float4*>(&Bs[k][tx*8+4]);
            float a[8] = {a0.x,a0.y,a0.z,a0.w,a1.x,a1.y,a1.z,a1.w};
            float b[8] = {b0.x,b0.y,b0.z,b0.w,b1.x,b1.y,b1.z,b1.w};
            #pragma unroll
            for (int i = 0; i < 8; ++i)
                #pragma unroll
                for (int j = 0; j < 8; ++j)
                    acc[i][j] = fmaf(a[i], b[j], acc[i][j]);
        }
    }

    #pragma unroll
    for (int i = 0; i < 8; ++i) {
        const int row = rowBase + ty * 8 + i;
        float* crow = C + (size_t)row * N;
        if constexpr (NVEC) {
            const int col = colBase + tx * 8;
            float v[8];
            #pragma unroll
            for (int j = 0; j < 8; ++j) {
                float t = acc[i][j] + bias[col + j];
                if constexpr (RELU) t = fmaxf(t, 0.f);
                v[j] = t;
            }
            *reinterpret_cast<float4*>(crow + col)     = make_float4(v[0],v[1],v[2],v[3]);
            *reinterpret_cast<float4*>(crow + col + 4) = make_float4(v[4],v[5],v[6],v[7]);
        } else {
            #pragma unroll
            for (int j = 0; j < 8; ++j) {
                const int col = colBase + tx * 8 + j;
                if (col < N) {
                    float t = acc[i][j] + bias[col];
                    if constexpr (RELU) t = fmaxf(t, 0.f);
                    crow[col] = t;
                }
            }
        }
    }
}

// ======================= VQ argmin (v2: gemm-structured) =======================
// Block = 128 rows, 256 threads, 8x8 micro-tile, BK=16.
// ct loop: 8 code-tiles of 128 codes covering all 1024 codes.
// score_k = ||e_k||^2 - 2 mu.e_k  (||mu||^2 cancels in comparisons).
// Running per-thread argmin across ct (thread's rows are ct-invariant).
// Tie-break = lowest code index (matches argmax(-dist) first-max semantics):
// within-thread codes are processed in ascending order w/ strict <; the
// cross-thread reduce does (v<bb)||(v==bb && vi<bi).
__global__ __launch_bounds__(256, 2)
void vq_k(const float* __restrict__ mu,     // [B,256]
          const float* __restrict__ embed,  // [256,1024]
          const float* __restrict__ e2,     // [1024]
          int* __restrict__ ind,
          unsigned int* __restrict__ hist,
          float* __restrict__ lossAcc)
{
    __shared__ float As[16][136];
    __shared__ float Es[16][128];
    __shared__ float e2s[KCODES];
    __shared__ float rbest[128][17];   // 17-pad: reduce reads conflict-free
    __shared__ int   ridx[128][17];
    __shared__ float mu2p[128][2];
    __shared__ float lrow[128];

    const int tid = threadIdx.x;
    const int tx = tid & 15, ty = tid >> 4;
    const int rowBase = blockIdx.x * 128;

    const int arow = tid >> 1;          // 0..127
    const int aseg = (tid & 1) * 8;     // 0/8
    const int brow = tid >> 4;          // 0..15 (k within tile)
    const int bcol = (tid & 15) * 8;    // 0..120 (code within tile)

    #pragma unroll
    for (int i = 0; i < 4; ++i) e2s[tid + i * 256] = e2[tid + i * 256];

    float best[8]; int bidx[8];
    #pragma unroll
    for (int i = 0; i < 8; ++i) { best[i] = 3.4e38f; bidx[i] = 0; }
    float mu2 = 0.f;

    for (int ct = 0; ct < 8; ++ct) {
        float acc[8][8];
        #pragma unroll
        for (int i = 0; i < 8; ++i)
            #pragma unroll
            for (int j = 0; j < 8; ++j) acc[i][j] = 0.f;

        for (int kt = 0; kt < 16; ++kt) {
            const int k0 = kt << 4;
            const float4* ap = reinterpret_cast<const float4*>(
                mu + (size_t)(rowBase + arow) * LATENT + (k0 + aseg));
            float4 a0 = ap[0], a1 = ap[1];
            const float* ebase = embed + (size_t)(k0 + brow) * KCODES + ct * 128 + bcol;
            float4 e0 = *reinterpret_cast<const float4*>(ebase);
            float4 e1 = *reinterpret_cast<const float4*>(ebase + 4);
            if (ct == 0)
                mu2 += a0.x*a0.x + a0.y*a0.y + a0.z*a0.z + a0.w*a0.w
                     + a1.x*a1.x + a1.y*a1.y + a1.z*a1.z + a1.w*a1.w;

            __syncthreads();
            As[aseg+0][arow] = a0.x; As[aseg+1][arow] = a0.y;
            As[aseg+2][arow] = a0.z; As[aseg+3][arow] = a0.w;
            As[aseg+4][arow] = a1.x; As[aseg+5][arow] = a1.y;
            As[aseg+6][arow] = a1.z; As[aseg+7][arow] = a1.w;
            *reinterpret_cast<float4*>(&Es[brow][bcol])     = e0;
            *reinterpret_cast<float4*>(&Es[brow][bcol + 4]) = e1;
            __syncthreads();

            #pragma unroll
            for (int k = 0; k < 16; ++k) {
                float4 A0 = *reinterpret_cast<const float4*>(&As[k][ty*8]);
                float4 A1 = *reinterpret_cast<const float4*>(&As[k][ty*8+4]);
                float4 B0 = *reinterpret_cast<const float4*>(&Es[k][tx*8]);
                float4 B1 = *reinterpret_cast<const float4*>(&Es[k][tx*8+4]);
                float a[8] = {A0.x,A0.y,A0.z,A0.w,A1.x,A1.y,A1.z,A1.w};
                float b[8] = {B0.x,B0.y,B0.z,B0.w,B1.x,B1.y,B1.z,B1.w};
                #pragma unroll
                for (int i = 0; i < 8; ++i)
                    #pragma unroll
                    for (int j = 0; j < 8; ++j)
                        acc[i][j] = fmaf(a[i], b[j], acc[i][j]);
            }
        }

        // fused argmin epilogue for this code-tile (codes ascend with j)
        #pragma unroll
        for (int j = 0; j < 8; ++j) {
            const int code = ct * 128 + tx * 8 + j;
            const float ev = e2s[code];
            #pragma unroll
            for (int i = 0; i < 8; ++i) {
                float s = fmaf(-2.f, acc[i][j], ev);
                if (s < best[i]) { best[i] = s; bidx[i] = code; }
            }
        }
    }

    // ---- cross-thread reduction ----
    #pragma unroll
    for (int i = 0; i < 8; ++i) { rbest[ty*8+i][tx] = best[i]; ridx[ty*8+i][tx] = bidx[i]; }
    mu2p[arow][tid & 1] = mu2;
    __syncthreads();

    if (tid < 128) {
        float bb = rbest[tid][0]; int bi = ridx[tid][0];
        #pragma unroll
        for (int t = 1; t < 16; ++t) {
            float v = rbest[tid][t]; int vi = ridx[tid][t];
            if (v < bb || (v == bb && vi < bi)) { bb = v; bi = vi; }
        }
        ind[rowBase + tid] = bi;
        atomicAdd(&hist[bi], 1u);
        float m2 = mu2p[tid][0] + mu2p[tid][1];
        lrow[tid] = m2 + bb;              // ||mu - e_best||^2
    }
    __syncthreads();
    if (tid == 0) {
        float s = 0.f;
        for (int r = 0; r < 128; ++r) s += lrow[r];
        atomicAdd(lossAcc, s);            // one atomic per block (1024 total)
    }
}

// ======================= small helpers =======================
__global__ void e2_k(const float* __restrict__ embed, float* __restrict__ e2)
{
    int n = blockIdx.x * 256 + threadIdx.x;   // 1024 total
    float s = 0.f;
    for (int d = 0; d < LATENT; ++d) {
        float v = embed[(size_t)d * KCODES + n];
        s = fmaf(v, v, s);
    }
    e2[n] = s;
}

__global__ void tr_k(const float* __restrict__ embed, float* __restrict__ embedT)
{
    __shared__ float t[32][33];
    const int tx = threadIdx.x & 31, ty = threadIdx.x >> 5;  // ty 0..7
    #pragma unroll
    for (int i = 0; i < 4; ++i) {
        int d = blockIdx.y * 32 + ty + i * 8;
        t[ty + i * 8][tx] = embed[(size_t)d * KCODES + blockIdx.x * 32 + tx];
    }
    __syncthreads();
    #pragma unroll
    for (int i = 0; i < 4; ++i) {
        int n = blockIdx.x * 32 + ty + i * 8;
        embedT[(size_t)n * LATENT + blockIdx.y * 32 + tx] = t[tx][ty + i * 8];
    }
}

__global__ void fin_k(const unsigned int* __restrict__ hist,
                      const float* __restrict__ lossAcc,
                      float* __restrict__ out2)
{
    __shared__ double sh[256];
    const int tid = threadIdx.x;
    double s = 0.0;
    for (int i = tid; i < KCODES; i += 256) {
        double p = (double)hist[i] / (double)BROWS;
        s += p * log(p + 1e-10);
    }
    sh[tid] = s; __syncthreads();
    for (int off = 128; off > 0; off >>= 1) {
        if (tid < off) sh[tid] += sh[tid + off];
        __syncthreads();
    }
    if (tid == 0) {
        out2[0] = lossAcc[0] / ((float)BROWS * (float)LATENT);   // loss
        out2[1] = (float)exp(-sh[0]);                            // perplexity
    }
}

// ======================= launch =======================
extern "C" void kernel_launch(void* const* d_in, const int* in_sizes, int n_in,
                              void* d_out, int out_size, void* d_ws, size_t ws_size,
                              hipStream_t stream)
{
    const float* x    = (const float*)d_in[0];
    const float* c    = (const float*)d_in[1];
    const float* W1   = (const float*)d_in[2];  const float* b1  = (const float*)d_in[3];
    const float* W2   = (const float*)d_in[4];  const float* b2  = (const float*)d_in[5];
    const float* W3   = (const float*)d_in[6];  const float* b3  = (const float*)d_in[7];
    const float* Wmu  = (const float*)d_in[8];  const float* bmu = (const float*)d_in[9];
    const float* W4   = (const float*)d_in[10]; const float* b4  = (const float*)d_in[11];
    const float* W5   = (const float*)d_in[12]; const float* b5  = (const float*)d_in[13];
    const float* W6   = (const float*)d_in[14]; const float* b6  = (const float*)d_in[15];
    const float* Wo   = (const float*)d_in[16]; const float* bo  = (const float*)d_in[17];
    const float* embed= (const float*)d_in[18];

    float* out = (float*)d_out;

    char* ws = (char*)d_ws;
    float* buf0 = (float*)ws;  ws += (size_t)BROWS * HDIM * sizeof(float);
    float* buf1 = (float*)ws;  ws += (size_t)BROWS * HDIM * sizeof(float);
    int*   ind  = (int*)ws;    ws += (size_t)BROWS * sizeof(int);
    float* embedT = (float*)ws; ws += (size_t)KCODES * LATENT * sizeof(float);
    float* e2   = (float*)ws;  ws += KCODES * sizeof(float);
    unsigned int* hist = (unsigned int*)ws; ws += KCODES * sizeof(unsigned int);
    float* lossAcc = (float*)ws; ws += 16;

    hipMemsetAsync(hist, 0, KCODES * sizeof(unsigned int) + 16, stream);
    e2_k<<<dim3(4), dim3(256), 0, stream>>>(embed, e2);
    tr_k<<<dim3(32, 8), dim3(256), 0, stream>>>(embed, embedT);

    const dim3 blk(256);
    const dim3 g512(4, BROWS / 128);
    const dim3 g256(2, BROWS / 128);
    const dim3 g267(3, BROWS / 128);

    // ---- encoder (fp32 to protect argmin) ----
    gemm_k<1, true,  true ><<<g512, blk, 0, stream>>>(nullptr, x, c, nullptr, nullptr, W1,  b1,  buf0, 512, 534);
    gemm_k<0, true,  true ><<<g512, blk, 0, stream>>>(buf0, nullptr, nullptr, nullptr, nullptr, W2,  b2,  buf1, 512, 512);
    gemm_k<0, true,  true ><<<g512, blk, 0, stream>>>(buf1, nullptr, nullptr, nullptr, nullptr, W3,  b3,  buf0, 512, 512);
    gemm_k<0, false, true ><<<g256, blk, 0, stream>>>(buf0, nullptr, nullptr, nullptr, nullptr, Wmu, bmu, buf1, 256, 512);

    // ---- vector quantizer (mu = buf1) ----
    vq_k<<<dim3(BROWS / 128), blk, 0, stream>>>(buf1, embed, e2, ind, hist, lossAcc);

    // ---- decoder ----
    gemm_k<2, true,  true ><<<g512, blk, 0, stream>>>(nullptr, nullptr, c, ind, embedT, W4, b4, buf0, 512, 523);
    gemm_k<0, true,  true ><<<g512, blk, 0, stream>>>(buf0, nullptr, nullptr, nullptr, nullptr, W5, b5, buf1, 512, 512);
    gemm_k<0, true,  true ><<<g512, blk, 0, stream>>>(buf1, nullptr, nullptr, nullptr, nullptr, W6, b6, buf0, 512, 512);
    gemm_k<0, false, false><<<g267, blk, 0, stream>>>(buf0, nullptr, nullptr, nullptr, nullptr, Wo, bo, out, 267, 512);

    // ---- loss + perplexity ----
    fin_k<<<dim3(1), dim3(256), 0, stream>>>(hist, lossAcc, out + (size_t)BROWS * FRAME);
}